// Round 4
// baseline (522.860 us; speedup 1.0000x reference)
//
#include <hip/hip_runtime.h>
#include <hip/hip_bf16.h>

#define B_   4
#define H_   16
#define LQ   1024
#define LK   2048
#define D_   1024
#define DH   64

typedef __attribute__((ext_vector_type(8))) short  short8;
typedef __attribute__((ext_vector_type(4))) float  float4_;
typedef __attribute__((ext_vector_type(4))) unsigned int uint4_;

static __device__ __forceinline__ float bf2f(unsigned short u) {
    unsigned int x = ((unsigned int)u) << 16;
    return __builtin_bit_cast(float, x);
}
static __device__ __forceinline__ unsigned short f2bf(float f) {
    unsigned int x = __builtin_bit_cast(unsigned int, f);
    unsigned int lsb = (x >> 16) & 1u;
    x += 0x7fffu + lsb;
    return (unsigned short)(x >> 16);
}
// pack 8 fp32 -> 8 bf16 in a uint4_
static __device__ __forceinline__ uint4_ pack8(float4_ a, float4_ b) {
    uint4_ o;
    o[0] = (unsigned int)f2bf(a[0]) | ((unsigned int)f2bf(a[1]) << 16);
    o[1] = (unsigned int)f2bf(a[2]) | ((unsigned int)f2bf(a[3]) << 16);
    o[2] = (unsigned int)f2bf(b[0]) | ((unsigned int)f2bf(b[1]) << 16);
    o[3] = (unsigned int)f2bf(b[2]) | ((unsigned int)f2bf(b[3]) << 16);
    return o;
}

#define MFMA(a, b, c) __builtin_amdgcn_mfma_f32_16x16x32_bf16((a), (b), (c), 0, 0, 0)

// ---------------------------------------------------------------------------
// Projection GEMM (fp32 in, bf16 staged): out = X @ W^T + bias.
// which 0: Q -> Qh[(b*H+h)*LQ + l][d]
// which 1: K -> Kh[(b*H+h)*LK + r][d]
// which 2: V -> VT[(b*H+h)*DH + d][r]   (transposed via LDS)
// 128x128 tile, BK=32, 256 threads (4 waves, each 64x64 via 4x4 mfma tiles).
// ---------------------------------------------------------------------------
__global__ __launch_bounds__(256) void proj_kernel(
    const float* __restrict__ Xq, const float* __restrict__ Xk,
    const float* __restrict__ Wq, const float* __restrict__ bq,
    const float* __restrict__ Wk, const float* __restrict__ bk,
    const float* __restrict__ Wv, const float* __restrict__ bv,
    unsigned short* __restrict__ Qh, unsigned short* __restrict__ Kh,
    unsigned short* __restrict__ VT)
{
    __shared__ short smem[17408];
    short* As = smem;                  // 128 x 40 bf16
    short* Bs = smem + 5120;           // 128 x 40 bf16
    short* Cs = smem;                  // 128 x 136 (V transpose, aliases)

    int bid = blockIdx.x;
    int which, tm, tn;
    const float *X, *W, *bias;
    if (bid < 256)      { which = 0; int t = bid;       tm = t >> 3; tn = t & 7; X = Xq; W = Wq; bias = bq; }
    else if (bid < 768) { which = 1; int t = bid - 256; tm = t >> 3; tn = t & 7; X = Xk; W = Wk; bias = bk; }
    else                { which = 2; int t = bid - 768; tm = t >> 3; tn = t & 7; X = Xk; W = Wv; bias = bv; }

    int tid  = threadIdx.x;
    int wave = tid >> 6, lane = tid & 63;
    int wr = (wave >> 1) * 64, wc = (wave & 1) * 64;
    int m0 = tm * 128, n0 = tn * 128;

    float4_ acc[4][4];
    for (int a = 0; a < 4; ++a) for (int c = 0; c < 4; ++c) acc[a][c] = (float4_)0.0f;

    int srow = tid >> 2, skp = (tid & 3) * 8;
    const float* Ag = X + (size_t)(m0 + srow) * D_ + skp;
    const float* Bg = W + (size_t)(n0 + srow) * D_ + skp;
    int lrow = lane & 15, lk8 = (lane >> 4) * 8;

    for (int kt = 0; kt < 32; ++kt) {
        int k0 = kt * 32;
        for (int i = 0; i < 2; ++i) {
            int row = srow + i * 64;
            const float* pa = Ag + (size_t)i * 64 * D_ + k0;
            const float* pb = Bg + (size_t)i * 64 * D_ + k0;
            float4_ a0 = *(const float4_*)(pa);
            float4_ a1 = *(const float4_*)(pa + 4);
            float4_ b0 = *(const float4_*)(pb);
            float4_ b1 = *(const float4_*)(pb + 4);
            *(uint4_*)(&As[row * 40 + skp]) = pack8(a0, a1);
            *(uint4_*)(&Bs[row * 40 + skp]) = pack8(b0, b1);
        }
        __syncthreads();
        short8 af[4], bfr[4];
        for (int rt = 0; rt < 4; ++rt) af[rt]  = *(const short8*)(&As[(wr + rt * 16 + lrow) * 40 + lk8]);
        for (int ct = 0; ct < 4; ++ct) bfr[ct] = *(const short8*)(&Bs[(wc + ct * 16 + lrow) * 40 + lk8]);
        for (int rt = 0; rt < 4; ++rt)
            for (int ct = 0; ct < 4; ++ct)
                acc[rt][ct] = MFMA(af[rt], bfr[ct], acc[rt][ct]);
        __syncthreads();
    }

    int lrow4 = (lane >> 4) * 4, lcol = lane & 15;
    if (which < 2) {
        int lsh = (which == 0) ? 10 : 11;          // LQ=1024, LK=2048
        int Lm1 = (1 << lsh) - 1;
        unsigned short* dst = (which == 0) ? Qh : Kh;
        for (int rt = 0; rt < 4; ++rt)
            for (int ct = 0; ct < 4; ++ct)
                for (int i = 0; i < 4; ++i) {
                    int m = m0 + wr + rt * 16 + lrow4 + i;
                    int n = n0 + wc + ct * 16 + lcol;
                    float v = acc[rt][ct][i] + bias[n];
                    int b = m >> lsh, s = m & Lm1;
                    int h = n >> 6, d = n & 63;
                    dst[((size_t)((b * H_ + h) << lsh) + (size_t)s) * DH + d] = f2bf(v);
                }
    } else {
        for (int rt = 0; rt < 4; ++rt)
            for (int ct = 0; ct < 4; ++ct)
                for (int i = 0; i < 4; ++i) {
                    int rl = wr + rt * 16 + lrow4 + i;   // tile row (seq)
                    int cl = wc + ct * 16 + lcol;        // tile col (h*64+d)
                    float v = acc[rt][ct][i] + bias[n0 + cl];
                    Cs[cl * 136 + rl] = (short)f2bf(v);
                }
        __syncthreads();
        int b = m0 >> 11, r0 = m0 & 2047;
        int c = tid >> 1, half = tid & 1;
        int n = n0 + c, h = n >> 6, d = n & 63;
        unsigned short* dstp = VT + ((size_t)(b * H_ + h) * DH + d) * LK + r0 + half * 64;
        for (int j = 0; j < 8; ++j) {
            uint4_ v = *(const uint4_*)(&Cs[c * 136 + half * 64 + j * 8]);
            *(uint4_*)(dstp + j * 8) = v;
        }
    }
}

// ---------------------------------------------------------------------------
// Flash attention with relative_key_query pe terms.
// E staged from fp32 dist_emb with fused bf16 convert; mask fp32; OUT fp32.
// ---------------------------------------------------------------------------
__global__ __launch_bounds__(256, 2) void attn_kernel(
    const unsigned short* __restrict__ Qh, const unsigned short* __restrict__ Kh,
    const unsigned short* __restrict__ VT, const float* __restrict__ Eg,
    const float* __restrict__ mask, float* __restrict__ out)
{
    __shared__ short smem[32256];        // 64512 B
    short* Qs  = smem;                   // 64 x 72
    short* Ks  = smem + 4608;            // 64 x 72
    short* VTs = smem + 9216;            // 64 x 72 (d-major: VTs[d][r])
    short* Es  = smem + 13824;           // 128 x 72
    short* Ps  = Es;                     // aliases Es (E dead by then)
    short* Gq2 = smem + 23040;           // 64 x 72  Gq2[tl][tr]
    short* Gk2 = smem + 27648;           // 64 x 72  Gk2[tr][tl]

    int bid = blockIdx.x;
    int l0 = (bid & 15) * 64;
    int bh = bid >> 4;
    int b  = bh >> 4, h = bh & 15;
    int tid = threadIdx.x, wave = tid >> 6, lane = tid & 63;
    int lrow = lane & 15, lk8 = (lane >> 4) * 8, lrow4 = (lane >> 4) * 4;

    // Stage Q tile once (bf16 source).
    for (int i = 0; i < 2; ++i) {
        int idx = tid + 256 * i, row = idx >> 3, g = (idx & 7) * 8;
        *(uint4_*)(&Qs[row * 72 + g]) =
            *(const uint4_*)(Qh + ((size_t)(bh * LQ + l0 + row)) * DH + g);
    }
    // zero-init gathered buffers once (exact range: 2304 ints = 4608 shorts each)
    for (int i = tid; i < 2304; i += 256) {
        ((int*)Gq2)[i] = 0;
        ((int*)Gk2)[i] = 0;
    }
    __syncthreads();
    short8 aq0 = *(const short8*)(&Qs[(wave * 16 + lrow) * 72 + lk8]);
    short8 aq1 = *(const short8*)(&Qs[(wave * 16 + lrow) * 72 + 32 + lk8]);

    float m_i[4], l_i[4];
    float4_ Oacc[4];
    for (int i = 0; i < 4; ++i) { m_i[i] = -1e30f; l_i[i] = 0.f; Oacc[i] = (float4_)0.f; }

    for (int it = 0; it < 32; ++it) {
        int r0 = it * 64;
        int jbase = l0 - r0 + 1984;      // in [0, 2944]; +127 <= 3071 < 4095

        for (int i = 0; i < 2; ++i) {
            int idx = tid + 256 * i, row = idx >> 3, g = (idx & 7) * 8;
            *(uint4_*)(&Ks[row * 72 + g]) =
                *(const uint4_*)(Kh + ((size_t)(bh * LK + r0 + row)) * DH + g);
            *(uint4_*)(&VTs[row * 72 + g]) =
                *(const uint4_*)(VT + ((size_t)(bh * DH + row)) * LK + r0 + g);
        }
        for (int i = 0; i < 4; ++i) {
            int idx = tid + 256 * i, row = idx >> 3, g = (idx & 7) * 8;
            const float* pe = Eg + ((size_t)(jbase + row)) * DH + g;
            float4_ e0 = *(const float4_*)(pe);
            float4_ e1 = *(const float4_*)(pe + 4);
            *(uint4_*)(&Es[row * 72 + g]) = pack8(e0, e1);
        }
        __syncthreads();

        // Q·K^T
        float4_ Sacc[4];
        for (int c = 0; c < 4; ++c) {
            short8 b0 = *(const short8*)(&Ks[(c * 16 + lrow) * 72 + lk8]);
            short8 b1 = *(const short8*)(&Ks[(c * 16 + lrow) * 72 + 32 + lk8]);
            float4_ s = (float4_)0.f;
            s = MFMA(aq0, b0, s);
            s = MFMA(aq1, b1, s);
            Sacc[c] = s;
        }

        // Gq (u-tiles wave..wave+4), Gk (u-tiles 3-wave..7-wave)
        short8 ak0 = *(const short8*)(&Ks[(wave * 16 + lrow) * 72 + lk8]);
        short8 ak1 = *(const short8*)(&Ks[(wave * 16 + lrow) * 72 + 32 + lk8]);
        float4_ Gq[5], Gk[5];
        for (int tt = 0; tt < 5; ++tt) {
            int tq = wave + tt;
            short8 e0 = *(const short8*)(&Es[(tq * 16 + lrow) * 72 + lk8]);
            short8 e1 = *(const short8*)(&Es[(tq * 16 + lrow) * 72 + 32 + lk8]);
            float4_ g = (float4_)0.f;
            g = MFMA(aq0, e0, g); g = MFMA(aq1, e1, g);
            Gq[tt] = g;
            int tk = (3 - wave) + tt;
            short8 f0 = *(const short8*)(&Es[(tk * 16 + lrow) * 72 + lk8]);
            short8 f1 = *(const short8*)(&Es[(tk * 16 + lrow) * 72 + 32 + lk8]);
            float4_ gg = (float4_)0.f;
            gg = MFMA(ak0, f0, gg); gg = MFMA(ak1, f1, gg);
            Gk[tt] = gg;
        }
        for (int tt = 0; tt < 5; ++tt) {
            int uq = (wave + tt) * 16 + lrow;
            int uk = (3 - wave + tt) * 16 + lrow;
            for (int i = 0; i < 4; ++i) {
                int row = wave * 16 + lrow4 + i;
                int tr = row - uq + 63;
                if (tr >= 0 && tr < 64) Gq2[row * 72 + tr] = (short)f2bf(Gq[tt][i]);
                int tl = uk + row - 63;
                if (tl >= 0 && tl < 64) Gk2[row * 72 + tl] = (short)f2bf(Gk[tt][i]);
            }
        }
        __syncthreads();

        // Assemble scores + online softmax.
        float mk[4];
        for (int c = 0; c < 4; ++c) mk[c] = mask[b * LK + r0 + c * 16 + lrow];
        float p[4][4];
        for (int i = 0; i < 4; ++i) {
            int tl = wave * 16 + lrow4 + i;
            float scv[4], mx = -1e30f;
            for (int c = 0; c < 4; ++c) {
                int tr = c * 16 + lrow;
                float sq = bf2f((unsigned short)Gq2[tl * 72 + tr]);
                float sk = bf2f((unsigned short)Gk2[tr * 72 + tl]);
                float sc = (Sacc[c][i] + sq + sk) * 0.125f + mk[c];
                scv[c] = sc;
                mx = fmaxf(mx, sc);
            }
            for (int off = 1; off < 16; off <<= 1) mx = fmaxf(mx, __shfl_xor(mx, off, 64));
            float mnew = fmaxf(m_i[i], mx);
            float alpha = __expf(m_i[i] - mnew);
            m_i[i] = mnew;
            float rs = 0.f;
            for (int c = 0; c < 4; ++c) {
                float e = __expf(scv[c] - mnew);
                e = bf2f(f2bf(e));            // round as stored: denom == MFMA numerator
                p[i][c] = e;
                rs += e;
            }
            for (int off = 1; off < 16; off <<= 1) rs += __shfl_xor(rs, off, 64);
            l_i[i] = l_i[i] * alpha + rs;
            for (int nt = 0; nt < 4; ++nt) Oacc[nt][i] *= alpha;
        }
        // Write P (own-wave rows; same-wave LDS RAW — keep compiler from reordering).
        for (int i = 0; i < 4; ++i) {
            int tl = wave * 16 + lrow4 + i;
            for (int c = 0; c < 4; ++c)
                Ps[tl * 72 + c * 16 + lrow] = (short)f2bf(p[i][c]);
        }
        __asm__ volatile("" ::: "memory");
        // P·V
        short8 ap0 = *(const short8*)(&Ps[(wave * 16 + lrow) * 72 + lk8]);
        short8 ap1 = *(const short8*)(&Ps[(wave * 16 + lrow) * 72 + 32 + lk8]);
        for (int nt = 0; nt < 4; ++nt) {
            short8 v0 = *(const short8*)(&VTs[(nt * 16 + lrow) * 72 + lk8]);
            short8 v1 = *(const short8*)(&VTs[(nt * 16 + lrow) * 72 + 32 + lk8]);
            Oacc[nt] = MFMA(ap0, v0, Oacc[nt]);
            Oacc[nt] = MFMA(ap1, v1, Oacc[nt]);
        }
        __syncthreads();
    }

    // Epilogue: out[b][l][h*64+d] = O / l_i   (fp32 output!)
    for (int nt = 0; nt < 4; ++nt)
        for (int i = 0; i < 4; ++i) {
            int row = l0 + wave * 16 + lrow4 + i;
            int col = h * 64 + nt * 16 + lrow;
            float v = Oacc[nt][i] / l_i[i];
            out[(size_t)(b * LQ + row) * D_ + col] = v;
        }
}

extern "C" void kernel_launch(void* const* d_in, const int* in_sizes, int n_in,
                              void* d_out, int out_size, void* d_ws, size_t ws_size,
                              hipStream_t stream) {
    (void)in_sizes; (void)n_in; (void)out_size; (void)ws_size;
    const float* Xk   = (const float*)d_in[0]; // hidden_states [4,2048,1024] fp32
    const float* Xq   = (const float*)d_in[1]; // query_hidden  [4,1024,1024] fp32
    const float* mask = (const float*)d_in[2]; // [4,1,1,2048] fp32
    const float* Wq   = (const float*)d_in[3];
    const float* bq   = (const float*)d_in[4];
    const float* Wk   = (const float*)d_in[5];
    const float* bk   = (const float*)d_in[6];
    const float* Wv   = (const float*)d_in[7];
    const float* bv   = (const float*)d_in[8];
    const float* Eg   = (const float*)d_in[9]; // dist_emb [4095,64] fp32

    // workspace: 42 MB total (Qh 8.4 MB + Kh 16.8 MB + VT 16.8 MB)
    unsigned short* Qh = (unsigned short*)d_ws;
    unsigned short* Kh = Qh + (size_t)B_ * H_ * LQ * DH;   // +4,194,304 elems
    unsigned short* VT = Kh + (size_t)B_ * H_ * LK * DH;   // +8,388,608 elems
    float* o = (float*)d_out;

    proj_kernel<<<1280, 256, 0, stream>>>(Xq, Xk, Wq, bq, Wk, bk, Wv, bv, Qh, Kh, VT);
    attn_kernel<<<1024, 256, 0, stream>>>(Qh, Kh, VT, Eg, mask, o);
}